// Round 9
// baseline (139.004 us; speedup 1.0000x reference)
//
#include <hip/hip_runtime.h>
#include <stdint.h>

// B=8 S=8192 E=1024 L=64 D=256 H=64; BS=65536; kv cols = 128 (k|v)
// fused: 64-token chunks, 1024 WGs -> 4 independent WGs/CU

typedef __attribute__((__ext_vector_type__(4))) float f32x4;
typedef __attribute__((__ext_vector_type__(8))) short bf16x8;

__device__ __forceinline__ unsigned short f2bf(float f) {
    union { float f; uint32_t u; } v; v.f = f;
    uint32_t u = v.u;
    return (unsigned short)((u + 0x7fffu + ((u >> 16) & 1u)) >> 16);  // RNE
}

__device__ __forceinline__ unsigned long long pack4(f32x4 v) {
    return (unsigned long long)f2bf(v[0])        |
           ((unsigned long long)f2bf(v[1]) << 16) |
           ((unsigned long long)f2bf(v[2]) << 32) |
           ((unsigned long long)f2bf(v[3]) << 48);
}

// ---------------- prep: Wkv -> bf16 ws, q = (latents @ Wq^T) * 0.125 -> bf16 ws
__global__ __launch_bounds__(256) void prep_kernel(
    const float* __restrict__ latents, const float* __restrict__ Wq,
    const float* __restrict__ Wk, const float* __restrict__ Wv,
    unsigned short* __restrict__ wkv, unsigned short* __restrict__ qbf)
{
    const int blk = blockIdx.x, tid = threadIdx.x;
    if (blk < 128) {
        const float* src = (blk < 64) ? (Wk + (size_t)blk * 1024)
                                      : (Wv + (size_t)(blk - 64) * 1024);
        for (int i = tid; i < 1024; i += 256)
            wkv[(size_t)blk * 1024 + i] = f2bf(src[i]);
    } else {
        const int l = (blk - 128) * 4 + (tid >> 6);
        const int h = tid & 63;
        float a = 0.f;
        #pragma unroll 8
        for (int d = 0; d < 256; ++d)
            a += latents[l * 256 + d] * Wq[h * 256 + d];
        qbf[l * 64 + h] = f2bf(a * 0.125f);
    }
}

// ---------------- fused: per (b, 64-key chunk):
//   kv tile (64 tokens x 128 cols) = x(f32->bf16) @ Wkv^T
//   A staged in LDS (R2 structure), B direct from L2-resident wkv
//   then scores=q@k^T, chunk softmax, O=P@v -> partials
__global__ __launch_bounds__(256, 4) void fused_kernel(
    const float* __restrict__ x, const unsigned short* __restrict__ wkv,
    const unsigned short* __restrict__ qbf,
    float* __restrict__ Opart, float* __restrict__ mpart, float* __restrict__ spart)
{
    __shared__ unsigned short smem[9856];    // 19.25 KiB total
    unsigned short* KV  = smem;              // [64][72]  K-half then V-half
    unsigned short* PsQ = smem + 4608;       // [64][72]  qs (scores) then Ps
    unsigned short* Ab  = smem;              // [2][64][40] staging (aliases, main loop only)
    __shared__ float red[4][64];
    __shared__ float Mrow[64];

    const int tid = threadIdx.x;
    const int wave = tid >> 6, lane = tid & 63;
    const int g = lane >> 4, c = lane & 15;
    const int wr = wave >> 1, wc = wave & 1;      // 2x2 wave grid over 64x128 tile
    const size_t r0 = (size_t)blockIdx.x * 64;    // token row base

    const int rowS = tid >> 2, c4 = (tid & 3) * 4;   // 4 lanes x f32x4, 64B contiguous

    f32x4 acc[2][4];
    #pragma unroll
    for (int i = 0; i < 2; ++i)
        #pragma unroll
        for (int j = 0; j < 4; ++j)
            acc[i][j] = f32x4{0.f, 0.f, 0.f, 0.f};

    f32x4 a0, a1;

    // prologue: stage K-step 0 into buf 0
    a0 = *(const f32x4*)(x + (r0 + rowS) * 1024 + c4);
    a1 = *(const f32x4*)(x + (r0 + rowS) * 1024 + c4 + 16);
    *(unsigned long long*)&Ab[rowS * 40 + c4]      = pack4(a0);
    *(unsigned long long*)&Ab[rowS * 40 + c4 + 16] = pack4(a1);
    __syncthreads();

    for (int t = 0; t < 32; ++t) {
        const int buf = t & 1;
        if (t < 31) {   // issue next-step A loads before compute
            const int e0 = (t + 1) * 32;
            a0 = *(const f32x4*)(x + (r0 + rowS) * 1024 + e0 + c4);
            a1 = *(const f32x4*)(x + (r0 + rowS) * 1024 + e0 + c4 + 16);
        }
        // B fragments direct from L2-resident wkv (bit-identical values)
        bf16x8 br[4];
        #pragma unroll
        for (int nc = 0; nc < 4; ++nc)
            br[nc] = *(const bf16x8*)(wkv + (size_t)(64 * wc + 16 * nc + c) * 1024
                                      + 32 * t + 8 * g);
        bf16x8 af[2];
        #pragma unroll
        for (int ml = 0; ml < 2; ++ml)
            af[ml] = *(const bf16x8*)&Ab[(buf * 64 + 32 * wr + 16 * ml + c) * 40 + 8 * g];
        #pragma unroll
        for (int ml = 0; ml < 2; ++ml)
            #pragma unroll
            for (int nc = 0; nc < 4; ++nc)
                acc[ml][nc] = __builtin_amdgcn_mfma_f32_16x16x32_bf16(
                    af[ml], br[nc], acc[ml][nc], 0, 0, 0);
        if (t < 31) {   // cvt + write into other buffer
            const int nb = buf ^ 1;
            *(unsigned long long*)&Ab[(nb * 64 + rowS) * 40 + c4]      = pack4(a0);
            *(unsigned long long*)&Ab[(nb * 64 + rowS) * 40 + c4 + 16] = pack4(a1);
        }
        __syncthreads();
    }

    // ---- attn phase 1: write K-half (wc==0 waves), stage q ----
    if (wc == 0)
        #pragma unroll
        for (int ml = 0; ml < 2; ++ml)
            #pragma unroll
            for (int nc = 0; nc < 4; ++nc)
                #pragma unroll
                for (int r = 0; r < 4; ++r)
                    KV[(32 * wr + 16 * ml + 4 * g + r) * 72 + 16 * nc + c] =
                        f2bf(acc[ml][nc][r]);
    {   // qs into PsQ (dead until scores; Ps overwrites it later)
        const int rowQ = tid >> 2, colQ = (tid & 3) * 8;
        #pragma unroll
        for (int j = 0; j < 2; ++j)
            *(uint4*)&PsQ[rowQ * 72 + colQ + 32 * j] =
                *(const uint4*)(qbf + rowQ * 64 + colQ + 32 * j);
    }
    __syncthreads();

    // ---- scores: wave w covers s in [16w,16w+16); D[row=l, col=s] ----
    f32x4 sc[4];
    #pragma unroll
    for (int ml = 0; ml < 4; ++ml) sc[ml] = f32x4{0.f, 0.f, 0.f, 0.f};
    #pragma unroll
    for (int k0 = 0; k0 < 2; ++k0) {
        bf16x8 bk = *(const bf16x8*)&KV[(16 * wave + c) * 72 + 32 * k0 + 8 * g];
        #pragma unroll
        for (int ml = 0; ml < 4; ++ml) {
            bf16x8 aq = *(const bf16x8*)&PsQ[(16 * ml + c) * 72 + 32 * k0 + 8 * g];
            sc[ml] = __builtin_amdgcn_mfma_f32_16x16x32_bf16(aq, bk, sc[ml], 0, 0, 0);
        }
    }

    // row max over this wave's 16 s (shuffle over c), cross-wave via red
    float mloc[4][4];
    #pragma unroll
    for (int ml = 0; ml < 4; ++ml)
        #pragma unroll
        for (int r = 0; r < 4; ++r)
            mloc[ml][r] = sc[ml][r];
    #pragma unroll
    for (int off = 1; off <= 8; off <<= 1)
        #pragma unroll
        for (int ml = 0; ml < 4; ++ml)
            #pragma unroll
            for (int r = 0; r < 4; ++r)
                mloc[ml][r] = fmaxf(mloc[ml][r], __shfl_xor(mloc[ml][r], off));
    if (c == 0)
        #pragma unroll
        for (int ml = 0; ml < 4; ++ml)
            #pragma unroll
            for (int r = 0; r < 4; ++r)
                red[wave][16 * ml + 4 * g + r] = mloc[ml][r];
    __syncthreads();
    if (tid < 64) {
        float m = red[0][tid];
        m = fmaxf(m, red[1][tid]); m = fmaxf(m, red[2][tid]); m = fmaxf(m, red[3][tid]);
        Mrow[tid] = m;
    }
    __syncthreads();

    // ---- softmax: P=exp(sc-M) bf16 into PsQ; V-half write (wc==1, K now dead) ----
    if (wc == 1)
        #pragma unroll
        for (int ml = 0; ml < 2; ++ml)
            #pragma unroll
            for (int nc = 0; nc < 4; ++nc)
                #pragma unroll
                for (int r = 0; r < 4; ++r)
                    KV[(32 * wr + 16 * ml + 4 * g + r) * 72 + 16 * nc + c] =
                        f2bf(acc[ml][nc][r]);
    float ssum[4][4];
    #pragma unroll
    for (int ml = 0; ml < 4; ++ml)
        #pragma unroll
        for (int r = 0; r < 4; ++r) {
            const int l = 16 * ml + 4 * g + r;
            float p = __expf(sc[ml][r] - Mrow[l]);
            unsigned short pb = f2bf(p);
            PsQ[l * 72 + 16 * wave + c] = pb;
            union { uint32_t u; float f; } pv; pv.u = (uint32_t)pb << 16;
            ssum[ml][r] = pv.f;   // rounded value for consistency
        }
    #pragma unroll
    for (int off = 1; off <= 8; off <<= 1)
        #pragma unroll
        for (int ml = 0; ml < 4; ++ml)
            #pragma unroll
            for (int r = 0; r < 4; ++r)
                ssum[ml][r] += __shfl_xor(ssum[ml][r], off);
    if (c == 0)
        #pragma unroll
        for (int ml = 0; ml < 4; ++ml)
            #pragma unroll
            for (int r = 0; r < 4; ++r)
                red[wave][16 * ml + 4 * g + r] = ssum[ml][r];
    __syncthreads();
    if (tid < 64) {
        const float s = red[0][tid] + red[1][tid] + red[2][tid] + red[3][tid];
        mpart[(size_t)blockIdx.x * 64 + tid] = Mrow[tid];
        spart[(size_t)blockIdx.x * 64 + tid] = s;
    }

    // ---- PV: wave w owns l in [16w,16w+16); D[row=l, col=h] ----
    f32x4 o[4];
    #pragma unroll
    for (int nh = 0; nh < 4; ++nh) o[nh] = f32x4{0.f, 0.f, 0.f, 0.f};
    #pragma unroll
    for (int ks = 0; ks < 2; ++ks) {
        bf16x8 ap = *(const bf16x8*)&PsQ[(16 * wave + c) * 72 + 32 * ks + 8 * g];
        #pragma unroll
        for (int nh = 0; nh < 4; ++nh) {
            bf16x8 bv;
            #pragma unroll
            for (int j = 0; j < 8; ++j)
                bv[j] = (short)KV[(32 * ks + 8 * g + j) * 72 + 16 * nh + c];
            o[nh] = __builtin_amdgcn_mfma_f32_16x16x32_bf16(ap, bv, o[nh], 0, 0, 0);
        }
    }
    const size_t pb = (size_t)blockIdx.x * 64;
    #pragma unroll
    for (int nh = 0; nh < 4; ++nh)
        #pragma unroll
        for (int r = 0; r < 4; ++r) {
            const int l = 16 * wave + 4 * g + r;
            const int h = 16 * nh + c;
            Opart[(pb + l) * 64 + h] = o[nh][r];
        }
}

// ---------------- combine: flash merge of 128 chunk partials per (b,l)
__global__ __launch_bounds__(64) void combine_kernel(
    const float* __restrict__ Opart, const float* __restrict__ mpart,
    const float* __restrict__ spart, float* __restrict__ out)
{
    const int b = blockIdx.x >> 6, l = blockIdx.x & 63, h = threadIdx.x;
    float M = -3.0e38f;
    #pragma unroll 8
    for (int ch = 0; ch < 128; ++ch)
        M = fmaxf(M, mpart[((size_t)(b * 128 + ch)) * 64 + l]);
    float den = 0.f, acc = 0.f;
    #pragma unroll 8
    for (int ch = 0; ch < 128; ++ch) {
        const size_t idx = ((size_t)(b * 128 + ch)) * 64 + l;
        const float w = __expf(mpart[idx] - M);
        den += w * spart[idx];
        acc += w * Opart[idx * 64 + h];
    }
    out[((size_t)blockIdx.x) * 64 + h] = acc / den;
}

extern "C" void kernel_launch(void* const* d_in, const int* in_sizes, int n_in,
                              void* d_out, int out_size, void* d_ws, size_t ws_size,
                              hipStream_t stream)
{
    const float* x       = (const float*)d_in[0];  // [8,8192,1024]
    const float* latents = (const float*)d_in[1];  // [64,256]
    const float* Wq      = (const float*)d_in[2];  // [64,256]
    const float* Wk      = (const float*)d_in[3];  // [64,1024]
    const float* Wv      = (const float*)d_in[4];  // [64,1024]
    float* out = (float*)d_out;                    // [8,64,64] f32
    char* ws = (char*)d_ws;

    unsigned short* wkv = (unsigned short*)(ws);                 // 262144 B
    unsigned short* qbf = (unsigned short*)(ws + 262144);        // 8192 B
    float* Opart = (float*)(ws + 270336);                        // 16777216 B
    float* mpart = (float*)(ws + 270336 + 16777216);             // 262144 B
    float* spart = (float*)(ws + 270336 + 16777216 + 262144);    // 262144 B

    hipLaunchKernelGGL(prep_kernel, dim3(144), dim3(256), 0, stream,
                       latents, Wq, Wk, Wv, wkv, qbf);
    hipLaunchKernelGGL(fused_kernel, dim3(1024), dim3(256), 0, stream,
                       x, wkv, qbf, Opart, mpart, spart);
    hipLaunchKernelGGL(combine_kernel, dim3(512), dim3(64), 0, stream,
                       Opart, mpart, spart, out);
}

// Round 10
// 85.972 us; speedup vs baseline: 1.6168x; 1.6168x over previous
//
#include <hip/hip_runtime.h>
#include <stdint.h>

// B=8 S=8192 E=1024 L=64 D=256 H=64; BS=65536; kv cols = 128 (k|v)

typedef __attribute__((__ext_vector_type__(4))) float f32x4;
typedef __attribute__((__ext_vector_type__(8))) short bf16x8;

__device__ __forceinline__ unsigned short f2bf(float f) {
    union { float f; uint32_t u; } v; v.f = f;
    uint32_t u = v.u;
    return (unsigned short)((u + 0x7fffu + ((u >> 16) & 1u)) >> 16);  // RNE
}

__device__ __forceinline__ unsigned long long pack4(f32x4 v) {
    return (unsigned long long)f2bf(v[0])        |
           ((unsigned long long)f2bf(v[1]) << 16) |
           ((unsigned long long)f2bf(v[2]) << 32) |
           ((unsigned long long)f2bf(v[3]) << 48);
}

__device__ __forceinline__ void gld_lds16(const void* g, void* l) {
    __builtin_amdgcn_global_load_lds(
        (const __attribute__((address_space(1))) unsigned int*)g,
        (__attribute__((address_space(3))) unsigned int*)l, 16, 0, 0);
}

// ---------------- prep: Wkv -> bf16 ws, q = (latents @ Wq^T) * 0.125 -> bf16 ws
__global__ __launch_bounds__(256) void prep_kernel(
    const float* __restrict__ latents, const float* __restrict__ Wq,
    const float* __restrict__ Wk, const float* __restrict__ Wv,
    unsigned short* __restrict__ wkv, unsigned short* __restrict__ qbf)
{
    const int blk = blockIdx.x, tid = threadIdx.x;
    if (blk < 128) {
        const float* src = (blk < 64) ? (Wk + (size_t)blk * 1024)
                                      : (Wv + (size_t)(blk - 64) * 1024);
        for (int i = tid; i < 1024; i += 256)
            wkv[(size_t)blk * 1024 + i] = f2bf(src[i]);
    } else {
        const int l = (blk - 128) * 4 + (tid >> 6);
        const int h = tid & 63;
        float a = 0.f;
        #pragma unroll 8
        for (int d = 0; d < 256; ++d)
            a += latents[l * 256 + d] * Wq[h * 256 + d];
        qbf[l * 64 + h] = f2bf(a * 0.125f);
    }
}

// ---------------- fused: per (b, 128-key chunk):
//   kv tile = x(f32) @ Wkv^T staged via global_load_lds (swizzled source),
//   f32->bf16 at LDS->fragment read; then scores/softmax/PV -> partials
__global__ __launch_bounds__(256, 2) void fused_kernel(
    const float* __restrict__ x, const unsigned short* __restrict__ wkv,
    const unsigned short* __restrict__ qbf,
    float* __restrict__ Opart, float* __restrict__ mpart, float* __restrict__ spart)
{
    __shared__ __align__(16) unsigned char smem[61440];    // 60 KiB
    float* Af          = (float*)smem;                     // [2][128][32] f32, linear, src-swizzled
    unsigned short* Bb = (unsigned short*)(smem + 32768);  // [2][128][32] sh, linear, src-swizzled
    unsigned short* Cs = (unsigned short*)smem;            // [128][136]  (attn, aliases Af)
    unsigned short* qs = (unsigned short*)(smem + 34816);  // [64][72]    (attn, aliases Bb)
    unsigned short* Ps = (unsigned short*)(smem + 44032);  // [64][136]   (attn, aliases Bb)
    __shared__ float red[4][64];
    __shared__ float Mrow[64];

    const int tid = threadIdx.x;
    const int wave = tid >> 6, lane = tid & 63;
    const int g = lane >> 4, c = lane & 15;
    const int wr = wave >> 1, wc = wave & 1;
    const size_t r0 = (size_t)blockIdx.x * 128;   // token row base (b*8192 + ch*128)

    // staging lane constants (source-address swizzle; LDS stays linear)
    const int arow = lane >> 3;                         // 0..7 within 8-row block
    const int agr  = (lane & 7) ^ arow;                 // A src granule (16B): ^= row&7
    const int brow = lane >> 2;                         // 0..15 within 16-row block
    const int bgr  = (lane & 3) ^ (brow & 3) ^ ((brow >> 2) & 3);  // B src granule

    const float* aSrc = x + (r0 + 8 * wave + arow) * 1024 + 4 * agr;
    const unsigned short* bSrc = wkv + (size_t)(16 * wave + brow) * 1024 + 8 * bgr;

    f32x4 acc[4][4];
    #pragma unroll
    for (int i = 0; i < 4; ++i)
        #pragma unroll
        for (int j = 0; j < 4; ++j)
            acc[i][j] = f32x4{0.f, 0.f, 0.f, 0.f};

    // prologue: stage K-step 0 into buf 0 (HW DMA, no VGPR round-trip)
    #pragma unroll
    for (int j = 0; j < 4; ++j)
        gld_lds16(aSrc + (size_t)j * 32 * 1024, Af + (32 * j + 8 * wave) * 32);
    #pragma unroll
    for (int j = 0; j < 2; ++j)
        gld_lds16(bSrc + (size_t)j * 64 * 1024, Bb + (64 * j + 16 * wave) * 32);
    __syncthreads();

    for (int t = 0; t < 32; ++t) {
        const int buf = t & 1;
        if (t < 31) {   // issue next-step DMA into the other buffer
            const int e0 = (t + 1) * 32;
            const int nb = buf ^ 1;
            #pragma unroll
            for (int j = 0; j < 4; ++j)
                gld_lds16(aSrc + (size_t)j * 32 * 1024 + e0,
                          Af + (nb * 128 + 32 * j + 8 * wave) * 32);
            #pragma unroll
            for (int j = 0; j < 2; ++j)
                gld_lds16(bSrc + (size_t)j * 64 * 1024 + e0,
                          Bb + (nb * 128 + 64 * j + 16 * wave) * 32);
        }
        // fragments from buf: A = 2x ds_read_b128 + pack (f32->bf16 here), B = 1x b128
        bf16x8 af[4], bfr[4];
        #pragma unroll
        for (int ml = 0; ml < 4; ++ml) {
            const float* base = Af + (buf * 128 + 64 * wr + 16 * ml + c) * 32;
            f32x4 u = *(const f32x4*)(base + 4 * ((2 * g)     ^ (c & 7)));
            f32x4 v = *(const f32x4*)(base + 4 * ((2 * g + 1) ^ (c & 7)));
            union { unsigned long long q[2]; bf16x8 b; } w;
            w.q[0] = pack4(u); w.q[1] = pack4(v);
            af[ml] = w.b;
        }
        #pragma unroll
        for (int nc = 0; nc < 4; ++nc)
            bfr[nc] = *(const bf16x8*)(Bb + (buf * 128 + 64 * wc + 16 * nc + c) * 32
                                       + 8 * (g ^ (c & 3) ^ ((c >> 2) & 3)));
        #pragma unroll
        for (int ml = 0; ml < 4; ++ml)
            #pragma unroll
            for (int nc = 0; nc < 4; ++nc)
                acc[ml][nc] = __builtin_amdgcn_mfma_f32_16x16x32_bf16(
                    af[ml], bfr[nc], acc[ml][nc], 0, 0, 0);
        __syncthreads();
    }

    // kv tile -> LDS (bf16), aliasing the staging buffers (all reads drained)
    #pragma unroll
    for (int ml = 0; ml < 4; ++ml)
        #pragma unroll
        for (int nc = 0; nc < 4; ++nc)
            #pragma unroll
            for (int r = 0; r < 4; ++r)
                Cs[(64 * wr + 16 * ml + 4 * g + r) * 136 + 64 * wc + 16 * nc + c] =
                    f2bf(acc[ml][nc][r]);
    // stage q (its slot aliases Bb, which is dead now)
    {
        const int rowQ = tid >> 2, colQ = (tid & 3) * 8;
        #pragma unroll
        for (int j = 0; j < 2; ++j)
            *(uint4*)&qs[rowQ * 72 + colQ + 32 * j] =
                *(const uint4*)(qbf + rowQ * 64 + colQ + 32 * j);
    }
    __syncthreads();

    // ---- attention on the LDS tile: cols 0..63 = k, 64..127 = v ----
    // scores: wave w covers s in [32w, 32w+32); D[row=l, col=s]
    f32x4 sc[4][2];
    #pragma unroll
    for (int ml = 0; ml < 4; ++ml)
        #pragma unroll
        for (int ns = 0; ns < 2; ++ns)
            sc[ml][ns] = f32x4{0.f, 0.f, 0.f, 0.f};
    #pragma unroll
    for (int k0 = 0; k0 < 2; ++k0) {
        bf16x8 aq[4];
        #pragma unroll
        for (int ml = 0; ml < 4; ++ml)
            aq[ml] = *(const bf16x8*)&qs[(16 * ml + c) * 72 + 32 * k0 + 8 * g];
        #pragma unroll
        for (int ns = 0; ns < 2; ++ns) {
            bf16x8 bk = *(const bf16x8*)&Cs[(32 * wave + 16 * ns + c) * 136 + 32 * k0 + 8 * g];
            #pragma unroll
            for (int ml = 0; ml < 4; ++ml)
                sc[ml][ns] = __builtin_amdgcn_mfma_f32_16x16x32_bf16(
                    aq[ml], bk, sc[ml][ns], 0, 0, 0);
        }
    }

    // row max: lane-local over ns, shuffle over the 16 s-lanes, combine 4 waves
    float mloc[4][4];
    #pragma unroll
    for (int ml = 0; ml < 4; ++ml)
        #pragma unroll
        for (int r = 0; r < 4; ++r)
            mloc[ml][r] = fmaxf(sc[ml][0][r], sc[ml][1][r]);
    #pragma unroll
    for (int off = 1; off <= 8; off <<= 1)
        #pragma unroll
        for (int ml = 0; ml < 4; ++ml)
            #pragma unroll
            for (int r = 0; r < 4; ++r)
                mloc[ml][r] = fmaxf(mloc[ml][r], __shfl_xor(mloc[ml][r], off));
    if (c == 0)
        #pragma unroll
        for (int ml = 0; ml < 4; ++ml)
            #pragma unroll
            for (int r = 0; r < 4; ++r)
                red[wave][16 * ml + 4 * g + r] = mloc[ml][r];
    __syncthreads();
    if (tid < 64) {
        float m = red[0][tid];
        m = fmaxf(m, red[1][tid]); m = fmaxf(m, red[2][tid]); m = fmaxf(m, red[3][tid]);
        Mrow[tid] = m;
    }
    __syncthreads();

    // P = exp(sc - M) (bf16 into LDS), row sums
    float ssum[4][4];
    #pragma unroll
    for (int ml = 0; ml < 4; ++ml)
        #pragma unroll
        for (int r = 0; r < 4; ++r)
            ssum[ml][r] = 0.f;
    #pragma unroll
    for (int ml = 0; ml < 4; ++ml)
        #pragma unroll
        for (int r = 0; r < 4; ++r) {
            const int l = 16 * ml + 4 * g + r;
            const float mr = Mrow[l];
            #pragma unroll
            for (int ns = 0; ns < 2; ++ns) {
                float p = __expf(sc[ml][ns][r] - mr);
                unsigned short pb = f2bf(p);
                Ps[l * 136 + 32 * wave + 16 * ns + c] = pb;
                union { uint32_t u; float f; } pv; pv.u = (uint32_t)pb << 16;
                ssum[ml][r] += pv.f;   // sum the rounded value for consistency
            }
        }
    #pragma unroll
    for (int off = 1; off <= 8; off <<= 1)
        #pragma unroll
        for (int ml = 0; ml < 4; ++ml)
            #pragma unroll
            for (int r = 0; r < 4; ++r)
                ssum[ml][r] += __shfl_xor(ssum[ml][r], off);
    if (c == 0)
        #pragma unroll
        for (int ml = 0; ml < 4; ++ml)
            #pragma unroll
            for (int r = 0; r < 4; ++r)
                red[wave][16 * ml + 4 * g + r] = ssum[ml][r];
    __syncthreads();
    if (tid < 64) {
        const float s = red[0][tid] + red[1][tid] + red[2][tid] + red[3][tid];
        mpart[(size_t)blockIdx.x * 64 + tid] = Mrow[tid];
        spart[(size_t)blockIdx.x * 64 + tid] = s;
    }

    // PV: wave w owns l in [16w,16w+16); D[row=l, col=h]
    f32x4 o[4];
    #pragma unroll
    for (int nh = 0; nh < 4; ++nh) o[nh] = f32x4{0.f, 0.f, 0.f, 0.f};
    #pragma unroll
    for (int ks = 0; ks < 4; ++ks) {
        bf16x8 ap = *(const bf16x8*)&Ps[(16 * wave + c) * 136 + 32 * ks + 8 * g];
        #pragma unroll
        for (int nh = 0; nh < 4; ++nh) {
            bf16x8 bv;
            #pragma unroll
            for (int j = 0; j < 8; ++j)
                bv[j] = (short)Cs[(32 * ks + 8 * g + j) * 136 + 64 + 16 * nh + c];
            o[nh] = __builtin_amdgcn_mfma_f32_16x16x32_bf16(ap, bv, o[nh], 0, 0, 0);
        }
    }
    const size_t pb = (size_t)blockIdx.x * 64;
    #pragma unroll
    for (int nh = 0; nh < 4; ++nh)
        #pragma unroll
        for (int r = 0; r < 4; ++r) {
            const int l = 16 * wave + 4 * g + r;
            const int h = 16 * nh + c;
            Opart[(pb + l) * 64 + h] = o[nh][r];
        }
}

// ---------------- combine: flash merge of 64 chunk partials per (b,l)
__global__ __launch_bounds__(64) void combine_kernel(
    const float* __restrict__ Opart, const float* __restrict__ mpart,
    const float* __restrict__ spart, float* __restrict__ out)
{
    const int b = blockIdx.x >> 6, l = blockIdx.x & 63, h = threadIdx.x;
    float M = -3.0e38f;
    #pragma unroll 8
    for (int ch = 0; ch < 64; ++ch)
        M = fmaxf(M, mpart[((size_t)(b * 64 + ch)) * 64 + l]);
    float den = 0.f, acc = 0.f;
    #pragma unroll 8
    for (int ch = 0; ch < 64; ++ch) {
        const size_t idx = ((size_t)(b * 64 + ch)) * 64 + l;
        const float w = __expf(mpart[idx] - M);
        den += w * spart[idx];
        acc += w * Opart[idx * 64 + h];
    }
    out[((size_t)blockIdx.x) * 64 + h] = acc / den;
}

extern "C" void kernel_launch(void* const* d_in, const int* in_sizes, int n_in,
                              void* d_out, int out_size, void* d_ws, size_t ws_size,
                              hipStream_t stream)
{
    const float* x       = (const float*)d_in[0];  // [8,8192,1024]
    const float* latents = (const float*)d_in[1];  // [64,256]
    const float* Wq      = (const float*)d_in[2];  // [64,256]
    const float* Wk      = (const float*)d_in[3];  // [64,1024]
    const float* Wv      = (const float*)d_in[4];  // [64,1024]
    float* out = (float*)d_out;                    // [8,64,64] f32
    char* ws = (char*)d_ws;

    unsigned short* wkv = (unsigned short*)(ws);                 // 262144 B
    unsigned short* qbf = (unsigned short*)(ws + 262144);        // 8192 B
    float* Opart = (float*)(ws + 270336);                        // 8388608 B
    float* mpart = (float*)(ws + 270336 + 8388608);              // 131072 B
    float* spart = (float*)(ws + 270336 + 8388608 + 131072);     // 131072 B

    hipLaunchKernelGGL(prep_kernel, dim3(144), dim3(256), 0, stream,
                       latents, Wq, Wk, Wv, wkv, qbf);
    hipLaunchKernelGGL(fused_kernel, dim3(512), dim3(256), 0, stream,
                       x, wkv, qbf, Opart, mpart, spart);
    hipLaunchKernelGGL(combine_kernel, dim3(512), dim3(64), 0, stream,
                       Opart, mpart, spart, out);
}